// Round 15
// baseline (41.582 us; speedup 1.0000x reference)
//
#include <hip/hip_runtime.h>

// CondConv2d B=16,CIN=COUT=128,H=W=56,E=4,3x3,pad=1 fp32.
// (1) mix: fold routing into bf16 Wmix[b][cc][tap][co][ci_l] (conv linear in W).
// (2) conv: block=(b, h-pair, px-half): 128co x 64px x K=1152 GEMM on
//     mfma_32x32x16_bf16. 896 blocks x 8 waves (wave 32co x 32px) ->
//     3 blocks/CU (42.6 KB LDS, launch_bounds(512,6)) = 24 waves/CU and
//     3 independent barrier domains per CU. A: global_load_lds 4-slab
//     counted-vmcnt rotation. B: x staged fp32->bf16 per ci-chunk
//     (72B row stride; halo covered by 34-col staging with OOB mask).

typedef float  f32x16 __attribute__((ext_vector_type(16)));
typedef short  s16x8  __attribute__((ext_vector_type(8)));
typedef unsigned short u16;

#define CIN   128
#define COUT  128
#define HH    56
#define WW    56
#define SP    (HH*WW)          // 3136
#define EW    147456           // per-expert W elems
#define BW_   147456           // per-sample Wmix elems: [cc4][tap9][co128][ci32]
#define XSTR  72               // xbuf col stride bytes (64 data + 8 pad)
#define XB2   (4*34*XSTR)      // 9792 B: 4 rows x 34 cols x 32ci bf16
#define AB    8192             // one A slab: 128 co x 32 ci bf16

static __device__ __forceinline__ u16 f2bf(float f) {
    unsigned u = __builtin_bit_cast(unsigned, f);
    return (u16)((u + 0x7FFFu + ((u >> 16) & 1u)) >> 16);
}

static __device__ __forceinline__ void gload16(const void* g, void* l) {
    __builtin_amdgcn_global_load_lds(
        (const __attribute__((address_space(1))) void*)g,
        (__attribute__((address_space(3))) void*)l, 16, 0, 0);
}

// ---------------------------------------------------------------------------
// mix: Wmix[b][cc][tap][co][ci_l] = sum_e r[b,e]*W[e][co][cc*32+ci_l][tap]
// ---------------------------------------------------------------------------
__global__ __launch_bounds__(256) void mix_kernel(const float* __restrict__ W,
                                                  const float* __restrict__ r,
                                                  u16* __restrict__ Wmix) {
    int o = blockIdx.x * 256 + threadIdx.x;      // [0, 147456)
    int ci_l = o & 31;
    int o2   = o >> 5;
    int co   = o2 & 127;
    int o3   = o2 >> 7;                          // [0,36)
    int tap  = o3 % 9;
    int cc   = o3 / 9;
    size_t src = ((size_t)co * CIN + cc*32 + ci_l) * 9 + tap;
    float w0 = W[src], w1 = W[src + EW], w2 = W[src + 2*EW], w3 = W[src + 3*EW];
    #pragma unroll
    for (int b = 0; b < 16; ++b) {
        float acc = r[b*4+0]*w0 + r[b*4+1]*w1 + r[b*4+2]*w2 + r[b*4+3]*w3;
        Wmix[(size_t)b * BW_ + o] = f2bf(acc);
    }
}

// ---------------------------------------------------------------------------
// conv. LDS: xbuf 9792 + 4 A slabs 32768 = 42560 B -> 3 blocks/CU (24 w/CU).
// ---------------------------------------------------------------------------
__global__ __launch_bounds__(512, 6) void conv_mfma(const float* __restrict__ x,
                                                    const u16* __restrict__ Wmix,
                                                    float* __restrict__ out) {
    __shared__ __align__(16) char ldsb[XB2 + 4*AB];

    const int bid = blockIdx.x;
    const int bs  = (bid & 7) * 112 + (bid >> 3);    // bijective XCD swizzle (896=8*112)
    const int b   = bs / 56;
    const int rem = bs % 56;
    const int ph  = rem >> 1;                        // rows {2ph, 2ph+1}
    const int pxh = rem & 1;                         // px half
    const int w0  = pxh * 32;
    const int t    = threadIdx.x;
    const int lane = t & 63;
    const int wid  = t >> 6;                         // 0..7
    const int wc   = wid & 3;                        // co quarter (32 co)
    const int wn   = wid >> 2;                       // output row within pair
    const int l31  = lane & 31;
    const int khalf= lane >> 5;

    const u16*   WmixB = Wmix + (size_t)b * BW_;
    const float* xbB   = x + (size_t)b * CIN * SP;

    // A DMA: lane source row = t>>2, dest slot = t&3, src slot inverse-swizzled
    const int ssl = (t & 3) ^ ((t >> 3) & 3);

    f32x16 acc = (f32x16)0.f;

    auto stageA = [&](int it) {
        char* ldst = ldsb + XB2 + (it & 3) * AB + wid * 1024;
        const u16* ga = WmixB + it * 4096 + (t >> 2) * 32 + ssl * 8;
        gload16(ga, ldst);
    };

    // B staging: xbuf[row 0..3][col 0..33][32 ci] bf16 for ci-chunk cc.
    // col c covers input w = w0 + c - 1 (halo included, OOB -> 0).
    auto stageX = [&](int cc) {
        for (int s = t; s < 544; s += 512) {
            int c    = s % 34;
            int rest = s / 34;                       // 0..15
            int row  = rest & 3;
            int g    = rest >> 2;                    // ci group 0..3
            int rr   = 2*ph - 1 + row;
            int w    = w0 + c - 1;
            bool ok  = ((unsigned)rr < 56u) && ((unsigned)w < 56u);
            const float* p = xbB + (size_t)(cc*32 + g*8) * SP + rr*56 + w;
            s16x8 v;
            #pragma unroll
            for (int j = 0; j < 8; ++j) {
                float f = ok ? p[(size_t)j * SP] : 0.f;
                v[j] = (short)f2bf(f);
            }
            *(s16x8*)(ldsb + (row*34 + c)*XSTR + g*16) = v;
        }
    };

    auto compute = [&](int n, int kh, int kw) {
        const char* Ab = ldsb + XB2 + (n & 3) * AB;
        s16x8 af[2], bv[2];
        #pragma unroll
        for (int ksub = 0; ksub < 2; ++ksub) {
            const int s = ksub * 2 + khalf;
            af[ksub] = *(const s16x8*)(Ab + (wc*32 + l31)*64
                                          + ((s ^ ((l31 >> 1) & 3)) * 16));
            const int c = l31 + kw;                  // 0..33
            bv[ksub] = *(const s16x8*)(ldsb + ((wn + kh)*34 + c)*XSTR + s*16);
        }
        #pragma unroll
        for (int ksub = 0; ksub < 2; ++ksub)
            acc = __builtin_amdgcn_mfma_f32_32x32x16_bf16(af[ksub], bv[ksub],
                                                          acc, 0, 0, 0);
    };

    // --- prologue: A slabs 0,1; x chunk 0 ---
    stageA(0);
    stageA(1);
    stageX(0);
    asm volatile("s_waitcnt lgkmcnt(0)" ::: "memory");
    __builtin_amdgcn_sched_barrier(0);
    __builtin_amdgcn_s_barrier();                    // slabs fly; xbuf(0) visible
    __builtin_amdgcn_sched_barrier(0);

    #pragma unroll
    for (int cc = 0; cc < 4; ++cc) {
        if (cc) {
            __builtin_amdgcn_sched_barrier(0);
            __builtin_amdgcn_s_barrier();            // all waves done reading xbuf
            __builtin_amdgcn_sched_barrier(0);
            stageX(cc);
            asm volatile("s_waitcnt lgkmcnt(0)" ::: "memory");
            __builtin_amdgcn_sched_barrier(0);
            __builtin_amdgcn_s_barrier();            // xbuf writes visible
            __builtin_amdgcn_sched_barrier(0);
        }
        #pragma unroll
        for (int tap = 0; tap < 9; ++tap) {
            const int n = cc * 9 + tap;
            if (n + 2 < 36) {
                stageA(n + 2);
                asm volatile("s_waitcnt vmcnt(2)" ::: "memory");  // slab n landed
            } else if (n + 1 < 36) {
                asm volatile("s_waitcnt vmcnt(1)" ::: "memory");
            } else {
                asm volatile("s_waitcnt vmcnt(0)" ::: "memory");
            }
            __builtin_amdgcn_s_barrier();
            __builtin_amdgcn_sched_barrier(0);
            __builtin_amdgcn_s_setprio(1);
            compute(n, tap / 3, tap % 3);
            __builtin_amdgcn_s_setprio(0);
        }
    }

    // store: D col(px)=l31, row(co) = (reg&3) + 8*(reg>>2) + 4*khalf
    const int w = w0 + l31;
    if (w < 56) {
        const int hrow = 2 * ph + wn;
        #pragma unroll
        for (int rg = 0; rg < 16; ++rg) {
            int co = wc*32 + (rg & 3) + 8*(rg >> 2) + 4*khalf;
            out[(((size_t)b*COUT + co)*HH + hrow)*WW + w] = acc[rg];
        }
    }
}

extern "C" void kernel_launch(void* const* d_in, const int* in_sizes, int n_in,
                              void* d_out, int out_size, void* d_ws, size_t ws_size,
                              hipStream_t stream) {
    const float* x = (const float*)d_in[0];          // [16,128,56,56]
    const float* r = (const float*)d_in[1];          // [16,4]
    const float* W = (const float*)d_in[2];          // [4,128,128,3,3]
    float* outp = (float*)d_out;                     // [16,128,56,56]
    u16* Wmix = (u16*)d_ws;                          // 4.72 MB

    mix_kernel<<<576, 256, 0, stream>>>(W, r, Wmix);
    conv_mfma <<<896, 512, 0, stream>>>(x, Wmix, outp);
}

// Round 16
// 34.798 us; speedup vs baseline: 1.1949x; 1.1949x over previous
//
#include <hip/hip_runtime.h>

// CondConv2d B=16,CIN=COUT=128,H=W=56,E=4,3x3,pad=1 fp32.
// (1) mix: fold routing into bf16 Wmix[b][cc][tap][co][ci_l] (conv linear in W).
// (2) conv: block=(b,h-pair): 128co x 128px x K=1152 GEMM on mfma_32x32x16_bf16.
//     R11 champion geometry (512 thr, 8 waves wm x wn x wp, wave 64co x 32px,
//     16 waves/CU) with BK=96 WINDOWS (3 taps each, 12 windows, cc-aligned):
//     T3 minimum-2-phase skeleton {stageA(w+1); compute 3 taps; vmcnt(0);
//     barrier} — 16 barriers total (was 44), vmcnt(0) drains under compute,
//     2x24KB A double-buffer (hazard-free: single bottom barrier separates
//     window w-1 readers from window w+1 staging).

typedef float  f32x16 __attribute__((ext_vector_type(16)));
typedef short  s16x8  __attribute__((ext_vector_type(8)));
typedef unsigned short u16;

#define CIN   128
#define COUT  128
#define HH    56
#define WW    56
#define SP    (HH*WW)          // 3136
#define EW    147456           // per-expert W elems
#define BW_   147456           // per-sample Wmix elems: [cc4][tap9][co128][ci32]
#define XSTR  72               // xbuf col stride bytes (64 data + 8 pad)
#define XB    (4*66*XSTR)      // 19008 B: 4 rows x 66 cols x 32ci bf16
#define WINB  24576            // one A window buffer: 3 slabs x 8192 B

static __device__ __forceinline__ u16 f2bf(float f) {
    unsigned u = __builtin_bit_cast(unsigned, f);
    return (u16)((u + 0x7FFFu + ((u >> 16) & 1u)) >> 16);
}

static __device__ __forceinline__ void gload16(const void* g, void* l) {
    __builtin_amdgcn_global_load_lds(
        (const __attribute__((address_space(1))) void*)g,
        (__attribute__((address_space(3))) void*)l, 16, 0, 0);
}

// ---------------------------------------------------------------------------
// mix: Wmix[b][cc][tap][co][ci_l] = sum_e r[b,e]*W[e][co][cc*32+ci_l][tap]
// ---------------------------------------------------------------------------
__global__ __launch_bounds__(256) void mix_kernel(const float* __restrict__ W,
                                                  const float* __restrict__ r,
                                                  u16* __restrict__ Wmix) {
    int o = blockIdx.x * 256 + threadIdx.x;      // [0, 147456)
    int ci_l = o & 31;
    int o2   = o >> 5;
    int co   = o2 & 127;
    int o3   = o2 >> 7;                          // [0,36)
    int tap  = o3 % 9;
    int cc   = o3 / 9;
    size_t src = ((size_t)co * CIN + cc*32 + ci_l) * 9 + tap;
    float w0 = W[src], w1 = W[src + EW], w2 = W[src + 2*EW], w3 = W[src + 3*EW];
    #pragma unroll
    for (int b = 0; b < 16; ++b) {
        float acc = r[b*4+0]*w0 + r[b*4+1]*w1 + r[b*4+2]*w2 + r[b*4+3]*w3;
        Wmix[(size_t)b * BW_ + o] = f2bf(acc);
    }
}

// ---------------------------------------------------------------------------
// conv. LDS: xbuf 19008 + 2 window bufs 49152 = 68160 B -> 2 blocks/CU.
// ---------------------------------------------------------------------------
__global__ __launch_bounds__(512, 4) void conv_mfma(const float* __restrict__ x,
                                                    const u16* __restrict__ Wmix,
                                                    float* __restrict__ out) {
    __shared__ __align__(16) char ldsb[XB + 2*WINB];

    const int bid = blockIdx.x;
    const int bs  = (bid & 7) * 56 + (bid >> 3);     // bijective XCD swizzle (448=8*56)
    const int b   = bs / 28;
    const int ph  = bs % 28;                         // rows {2ph, 2ph+1}
    const int t    = threadIdx.x;
    const int lane = t & 63;
    const int wid  = t >> 6;                         // 0..7
    const int wm   = (wid >> 2) & 1;                 // co half
    const int wn   = (wid >> 1) & 1;                 // output row within pair
    const int wp   = wid & 1;                        // px half
    const int l31  = lane & 31;
    const int khalf= lane >> 5;

    const u16*   WmixB = Wmix + (size_t)b * BW_;
    const float* xbB   = x + (size_t)b * CIN * SP;

    // A DMA: lane source row = t>>2, dest slot = t&3, src slot inverse-swizzled
    const int ssl = (t & 3) ^ ((t >> 3) & 3);

    f32x16 acc[2];
    acc[0] = (f32x16)0.f;
    acc[1] = (f32x16)0.f;

    // stage 3 A slabs (3w..3w+2) into window buffer w&1
    auto stageA3 = [&](int w) {
        char* buf = ldsb + XB + (w & 1) * WINB + wid * 1024;
        const u16* ga = WmixB + (size_t)(3*w) * 4096 + (t >> 2) * 32 + ssl * 8;
        gload16(ga,        buf);
        gload16(ga + 4096, buf + 8192);
        gload16(ga + 8192, buf + 16384);
    };

    // B staging: xbuf[row 0..3][col 0..65][32 ci] bf16 for ci-chunk cc
    auto stageX = [&](int cc) {
        #pragma unroll
        for (int i = 0; i < 2; ++i) {
            int slot = i * 512 + t;                  // 0..1023
            int c    = 1 + (slot & 63);              // col 1..64
            int row  = (slot >> 6) & 3;              // 0..3
            int g    = slot >> 8;                    // ci group 0..3
            int rr   = 2*ph - 1 + row;               // input row
            int w    = c - 1;
            bool ok  = ((unsigned)rr < 56u) && (w < 56);
            const float* p = xbB + (size_t)(cc*32 + g*8) * SP + rr*56 + w;
            s16x8 v;
            #pragma unroll
            for (int j = 0; j < 8; ++j) {
                float f = ok ? p[(size_t)j * SP] : 0.f;
                v[j] = (short)f2bf(f);
            }
            *(s16x8*)(ldsb + (row*66 + c)*XSTR + g*16) = v;
        }
    };

    // compute the 3 taps of window w (A buf w&1; 18 ds_read + 12 MFMA / wave)
    auto compute3 = [&](int w) {
        const char* Ab = ldsb + XB + (w & 1) * WINB;
        #pragma unroll
        for (int j = 0; j < 3; ++j) {
            const int tap = (w % 3) * 3 + j;         // compile-time (unrolled)
            const int kh  = tap / 3;
            const int kw  = tap % 3;
            #pragma unroll
            for (int ksub = 0; ksub < 2; ++ksub) {
                const int s = ksub * 2 + khalf;
                s16x8 af0 = *(const s16x8*)(Ab + j*8192 + (wm*64 + l31)*64
                                               + ((s ^ ((l31 >> 1) & 3)) * 16));
                s16x8 af1 = *(const s16x8*)(Ab + j*8192 + (wm*64 + 32 + l31)*64
                                               + ((s ^ ((l31 >> 1) & 3)) * 16));
                const int c = wp*32 + l31 + kw;      // 0..65
                s16x8 bv  = *(const s16x8*)(ldsb + ((wn + kh)*66 + c)*XSTR + s*16);
                acc[0] = __builtin_amdgcn_mfma_f32_32x32x16_bf16(af0, bv, acc[0], 0, 0, 0);
                acc[1] = __builtin_amdgcn_mfma_f32_32x32x16_bf16(af1, bv, acc[1], 0, 0, 0);
            }
        }
    };

    // --- prologue: zero halo cols; A window 0; xbuf chunk 0 ---
    if (t < 32) {
        int row = t >> 3, col = ((t >> 2) & 1) ? 65 : 0, sl = t & 3;
        *(s16x8*)(ldsb + (row*66 + col)*XSTR + sl*16) = (s16x8)0;
    }
    stageA3(0);
    stageX(0);
    asm volatile("s_waitcnt vmcnt(0) lgkmcnt(0)" ::: "memory");
    __builtin_amdgcn_sched_barrier(0);
    __builtin_amdgcn_s_barrier();                    // slabs 0-2 + xbuf(0) visible
    __builtin_amdgcn_sched_barrier(0);

    #pragma unroll
    for (int w = 0; w < 12; ++w) {
        if (w && (w % 3) == 0) {
            // cc boundary: all waves passed bottom barrier of w-1 (done with
            // old xbuf). Restage xbuf, publish, then proceed.
            stageX(w / 3);
            asm volatile("s_waitcnt lgkmcnt(0)" ::: "memory");
            __builtin_amdgcn_sched_barrier(0);
            __builtin_amdgcn_s_barrier();            // xbuf(cc) visible
            __builtin_amdgcn_sched_barrier(0);
        }
        if (w + 1 < 12) stageA3(w + 1);              // DMA -> buf (w+1)&1
        __builtin_amdgcn_s_setprio(1);
        compute3(w);                                 // reads buf w&1 + xbuf
        __builtin_amdgcn_s_setprio(0);
        asm volatile("s_waitcnt vmcnt(0)" ::: "memory");  // drained under compute
        __builtin_amdgcn_sched_barrier(0);
        __builtin_amdgcn_s_barrier();                // publish buf (w+1)&1
        __builtin_amdgcn_sched_barrier(0);
    }

    // store: D col(px)=l31, row(co) = (reg&3) + 8*(reg>>2) + 4*khalf
    const int w = wp * 32 + l31;
    if (w < 56) {
        const int hrow = 2 * ph + wn;
        #pragma unroll
        for (int mf = 0; mf < 2; ++mf) {
            #pragma unroll
            for (int rg = 0; rg < 16; ++rg) {
                int co = wm*64 + mf*32 + (rg & 3) + 8*(rg >> 2) + 4*khalf;
                out[(((size_t)b*COUT + co)*HH + hrow)*WW + w] = acc[mf][rg];
            }
        }
    }
}

extern "C" void kernel_launch(void* const* d_in, const int* in_sizes, int n_in,
                              void* d_out, int out_size, void* d_ws, size_t ws_size,
                              hipStream_t stream) {
    const float* x = (const float*)d_in[0];          // [16,128,56,56]
    const float* r = (const float*)d_in[1];          // [16,4]
    const float* W = (const float*)d_in[2];          // [4,128,128,3,3]
    float* outp = (float*)d_out;                     // [16,128,56,56]
    u16* Wmix = (u16*)d_ws;                          // 4.72 MB

    mix_kernel<<<576, 256, 0, stream>>>(W, r, Wmix);
    conv_mfma <<<448, 512, 0, stream>>>(x, Wmix, outp);
}

// Round 17
// 34.406 us; speedup vs baseline: 1.2085x; 1.0114x over previous
//
#include <hip/hip_runtime.h>

// CondConv2d B=16,CIN=COUT=128,H=W=56,E=4,3x3,pad=1 fp32.
// (1) mix: fold routing into bf16 Wmix[b][cc][tap][co][ci_l] (conv linear in W).
//     v2: thread=(co,ci) reads 36 contiguous bytes/expert (no stride-9
//     amplification); writes wave-contiguous. Grid (64, b-quad).
// (2) conv: R11 champion verbatim (best measured): block=(b,h-pair),
//     128co x 128px x K=1152 GEMM on mfma_32x32x16_bf16, 512 thr / 8 waves,
//     A: global_load_lds 4-slab counted-vmcnt rotation, B: x staged
//     fp32->bf16 per ci-chunk (72B row stride).

typedef float  f32x16 __attribute__((ext_vector_type(16)));
typedef short  s16x8  __attribute__((ext_vector_type(8)));
typedef unsigned short u16;

#define CIN   128
#define COUT  128
#define HH    56
#define WW    56
#define SP    (HH*WW)          // 3136
#define EW    147456           // per-expert W elems
#define BW_   147456           // per-sample Wmix elems: [cc4][tap9][co128][ci32]
#define XSTR  72               // xbuf row stride bytes (64 data + 8 pad)
#define XB    (4*66*XSTR)      // 19008 B
#define AB    8192             // one A slab: 128 co x 32 ci bf16

static __device__ __forceinline__ u16 f2bf(float f) {
    unsigned u = __builtin_bit_cast(unsigned, f);
    return (u16)((u + 0x7FFFu + ((u >> 16) & 1u)) >> 16);
}

static __device__ __forceinline__ void gload16(const void* g, void* l) {
    __builtin_amdgcn_global_load_lds(
        (const __attribute__((address_space(1))) void*)g,
        (__attribute__((address_space(3))) void*)l, 16, 0, 0);
}

// ---------------------------------------------------------------------------
// mix v2: Wmix[b][cc][tap][co][ci_l] = sum_e r[b,e]*W[e][co][ci][tap]
// thread o = (co,ci): reads W[e][co][ci][0..8] contiguous (36B) per expert;
// grid.y = 4 b-quads (W re-read 4x, L2-resident). Writes: lanes span ci_l ->
// 64B-contiguous per 32 lanes.
// ---------------------------------------------------------------------------
__global__ __launch_bounds__(256) void mix_kernel(const float* __restrict__ W,
                                                  const float* __restrict__ r,
                                                  u16* __restrict__ Wmix) {
    const int o  = blockIdx.x * 256 + threadIdx.x;   // [0, 16384) = (co, ci)
    const int ci = o & 127;
    const int co = o >> 7;
    const int cc   = ci >> 5;
    const int ci_l = ci & 31;
    const int bq   = blockIdx.y;                     // b-quad

    float wv[4][9];
    const float* src = W + ((size_t)co * CIN + ci) * 9;
    #pragma unroll
    for (int e = 0; e < 4; ++e)
        #pragma unroll
        for (int tap = 0; tap < 9; ++tap)
            wv[e][tap] = src[(size_t)e * EW + tap];

    #pragma unroll
    for (int bb = 0; bb < 4; ++bb) {
        const int b = bq * 4 + bb;
        const float r0 = r[b*4+0], r1 = r[b*4+1], r2 = r[b*4+2], r3 = r[b*4+3];
        #pragma unroll
        for (int tap = 0; tap < 9; ++tap) {
            float acc = r0*wv[0][tap] + r1*wv[1][tap]
                      + r2*wv[2][tap] + r3*wv[3][tap];
            Wmix[(size_t)b * BW_ + (((cc*9 + tap)*128 + co) << 5) + ci_l] = f2bf(acc);
        }
    }
}

// ---------------------------------------------------------------------------
// conv (R11 champion). LDS: xbuf 19008 + 4 A slabs 32768 = 51776 B.
// ---------------------------------------------------------------------------
__global__ __launch_bounds__(512, 4) void conv_mfma(const float* __restrict__ x,
                                                    const u16* __restrict__ Wmix,
                                                    float* __restrict__ out) {
    __shared__ __align__(16) char ldsb[XB + 4*AB];

    const int bid = blockIdx.x;
    const int bs  = (bid & 7) * 56 + (bid >> 3);     // bijective XCD swizzle (448=8*56)
    const int b   = bs / 28;
    const int ph  = bs % 28;                         // rows {2ph, 2ph+1}
    const int t    = threadIdx.x;
    const int lane = t & 63;
    const int wid  = t >> 6;                         // 0..7
    const int wm   = (wid >> 2) & 1;                 // co half
    const int wn   = (wid >> 1) & 1;                 // output row within pair
    const int wp   = wid & 1;                        // px half
    const int l31  = lane & 31;
    const int khalf= lane >> 5;

    const u16*   WmixB = Wmix + (size_t)b * BW_;
    const float* xbB   = x + (size_t)b * CIN * SP;

    // A DMA: lane source row = t>>2, dest slot = t&3, src slot inverse-swizzled
    const int ssl = (t & 3) ^ ((t >> 3) & 3);

    f32x16 acc[2];
    acc[0] = (f32x16)0.f;
    acc[1] = (f32x16)0.f;

    auto stageA = [&](int it) {
        char* ldst = ldsb + XB + (it & 3) * AB + wid * 1024;
        const u16* ga = WmixB + it * 4096 + (t >> 2) * 32 + ssl * 8;
        gload16(ga, ldst);
    };

    // B staging: xbuf[row 0..3][col 0..65][32 ci] bf16 for ci-chunk cc
    auto stageX = [&](int cc) {
        #pragma unroll
        for (int i = 0; i < 2; ++i) {
            int slot = i * 512 + t;                  // 0..1023
            int c    = 1 + (slot & 63);              // col 1..64
            int row  = (slot >> 6) & 3;              // 0..3
            int g    = slot >> 8;                    // ci group 0..3
            int rr   = 2*ph - 1 + row;               // input row
            int w    = c - 1;
            bool ok  = ((unsigned)rr < 56u) && (w < 56);
            const float* p = xbB + (size_t)(cc*32 + g*8) * SP + rr*56 + w;
            s16x8 v;
            #pragma unroll
            for (int j = 0; j < 8; ++j) {
                float f = ok ? p[(size_t)j * SP] : 0.f;
                v[j] = (short)f2bf(f);
            }
            *(s16x8*)(ldsb + (row*66 + c)*XSTR + g*16) = v;
        }
    };

    auto compute = [&](int it, int kh, int kw) {
        const char* Ab = ldsb + XB + (it & 3) * AB;
        #pragma unroll
        for (int ksub = 0; ksub < 2; ++ksub) {
            const int s = ksub * 2 + khalf;
            s16x8 af[2], bv;
            #pragma unroll
            for (int mf = 0; mf < 2; ++mf)
                af[mf] = *(const s16x8*)(Ab + (wm*64 + mf*32 + l31)*64
                                            + ((s ^ ((l31 >> 1) & 3)) * 16));
            const int c = wp*32 + l31 + kw;          // 0..65
            bv = *(const s16x8*)(ldsb + ((wn + kh)*66 + c)*XSTR + s*16);
            #pragma unroll
            for (int mf = 0; mf < 2; ++mf)
                acc[mf] = __builtin_amdgcn_mfma_f32_32x32x16_bf16(
                    af[mf], bv, acc[mf], 0, 0, 0);
        }
    };

    // --- prologue: zero halo cols (c=0,65); A slabs 0,1; x chunk 0 ---
    if (t < 32) {
        int row = t >> 3, col = ((t >> 2) & 1) ? 65 : 0, sl = t & 3;
        *(s16x8*)(ldsb + (row*66 + col)*XSTR + sl*16) = (s16x8)0;
    }
    stageA(0);
    stageA(1);
    stageX(0);
    asm volatile("s_waitcnt lgkmcnt(0)" ::: "memory");
    __builtin_amdgcn_sched_barrier(0);
    __builtin_amdgcn_s_barrier();                    // slabs fly; xbuf(0) visible
    __builtin_amdgcn_sched_barrier(0);

    #pragma unroll
    for (int cc = 0; cc < 4; ++cc) {
        if (cc) {
            __builtin_amdgcn_sched_barrier(0);
            __builtin_amdgcn_s_barrier();            // all waves done reading xbuf
            __builtin_amdgcn_sched_barrier(0);
            stageX(cc);
            asm volatile("s_waitcnt lgkmcnt(0)" ::: "memory");
            __builtin_amdgcn_sched_barrier(0);
            __builtin_amdgcn_s_barrier();            // xbuf writes visible
            __builtin_amdgcn_sched_barrier(0);
        }
        #pragma unroll
        for (int tap = 0; tap < 9; ++tap) {
            const int it = cc * 9 + tap;
            if (it + 2 < 36) {
                stageA(it + 2);                      // 1 DMA instr per wave
                asm volatile("s_waitcnt vmcnt(2)" ::: "memory");  // it's slab landed
            } else if (it + 1 < 36) {
                asm volatile("s_waitcnt vmcnt(1)" ::: "memory");
            } else {
                asm volatile("s_waitcnt vmcnt(0)" ::: "memory");
            }
            __builtin_amdgcn_s_barrier();
            __builtin_amdgcn_sched_barrier(0);
            __builtin_amdgcn_s_setprio(1);
            compute(it, tap / 3, tap % 3);
            __builtin_amdgcn_s_setprio(0);
        }
    }

    // store: D col(px)=l31, row(co) = (reg&3) + 8*(reg>>2) + 4*khalf
    const int w = wp * 32 + l31;
    if (w < 56) {
        const int hrow = 2 * ph + wn;
        #pragma unroll
        for (int mf = 0; mf < 2; ++mf) {
            #pragma unroll
            for (int rg = 0; rg < 16; ++rg) {
                int co = wm*64 + mf*32 + (rg & 3) + 8*(rg >> 2) + 4*khalf;
                out[(((size_t)b*COUT + co)*HH + hrow)*WW + w] = acc[mf][rg];
            }
        }
    }
}

extern "C" void kernel_launch(void* const* d_in, const int* in_sizes, int n_in,
                              void* d_out, int out_size, void* d_ws, size_t ws_size,
                              hipStream_t stream) {
    const float* x = (const float*)d_in[0];          // [16,128,56,56]
    const float* r = (const float*)d_in[1];          // [16,4]
    const float* W = (const float*)d_in[2];          // [4,128,128,3,3]
    float* outp = (float*)d_out;                     // [16,128,56,56]
    u16* Wmix = (u16*)d_ws;                          // 4.72 MB

    mix_kernel<<<dim3(64, 4), 256, 0, stream>>>(W, r, Wmix);
    conv_mfma <<<448, 512, 0, stream>>>(x, Wmix, outp);
}